// Round 8
// baseline (90.160 us; speedup 1.0000x reference)
//
#include <hip/hip_runtime.h>
#include <math.h>

// Problem constants
#define NB    32
#define NHEAD 16
#define HW    1024

typedef float f32x4  __attribute__((ext_vector_type(4)));
typedef short bf16x2 __attribute__((ext_vector_type(2)));
typedef short bf16x4 __attribute__((ext_vector_type(4)));
typedef short bf16x8 __attribute__((ext_vector_type(8)));

__device__ __forceinline__ short f2bf(float f) {   // fp32 -> bf16 RNE
    union { float f; unsigned u; } c; c.f = f;
    unsigned r = c.u + 0x7FFFu + ((c.u >> 16) & 1u);
    return (short)(r >> 16);
}
#define SWZ(row)  ((((row) >> 1) & 7) << 4)   // for 128-B-pitch rows
#define SW64(x)   ((((x) >> 1) & 3) << 4)     // for 64-B-pitch rows
#define MFMA16(a, b, c) __builtin_amdgcn_mfma_f32_16x16x32_bf16(a, b, c, 0, 0, 0)

__device__ __forceinline__ bf16x8 lds_ld8(const short* base, int off) {
    return *(const bf16x8*)((const char*)base + off);
}
__device__ __forceinline__ void lds_st4(short* base, int off, bf16x4 v) {
    *(bf16x4*)((char*)base + off) = v;
}

// ---------------------------------------------------------------------------
// Kernel 0: prep — bf16 casts / transposes / bias fold. (unchanged, passes)
// ---------------------------------------------------------------------------
__global__ __launch_bounds__(256) void prep_kernel(
        const float* __restrict__ Wq, const float* __restrict__ token,
        const float* __restrict__ Wk, const float* __restrict__ bq,
        short* __restrict__ Wq_bf, short* __restrict__ tok_t,
        short* __restrict__ Wk_t, float* __restrict__ qkb) {
    __shared__ float red[256];
    const int b = blockIdx.x, t = threadIdx.x;
    if (b < 1024) {
        const size_t idx = (size_t)b * 1024 + t * 4;
        const f32x4 v = *(const f32x4*)(Wq + idx);
        bf16x4 o; o[0]=f2bf(v[0]); o[1]=f2bf(v[1]); o[2]=f2bf(v[2]); o[3]=f2bf(v[3]);
        *(bf16x4*)(Wq_bf + idx) = o;
    } else if (b < 1056) {
        const int n = b - 1024;
        const int c0 = t * 4;
        float arr[4][16];
#pragma unroll
        for (int ci = 0; ci < 4; ++ci)
#pragma unroll
            for (int lq = 0; lq < 4; ++lq) {
                const f32x4 v = *(const f32x4*)(token + (size_t)n*16384 + (size_t)(c0+ci)*16 + lq*4);
#pragma unroll
                for (int e = 0; e < 4; ++e) arr[ci][lq*4+e] = v[e];
            }
#pragma unroll
        for (int l = 0; l < 16; ++l) {
            bf16x4 o; o[0]=f2bf(arr[0][l]); o[1]=f2bf(arr[1][l]); o[2]=f2bf(arr[2][l]); o[3]=f2bf(arr[3][l]);
            *(bf16x4*)(tok_t + (size_t)n*16384 + (size_t)l*1024 + c0) = o;
        }
    } else {
        const int h = b - 1056;
        const int i = t & 63, dq = t >> 6;
        float qs = 0.f; short wt[16];
#pragma unroll
        for (int k = 0; k < 16; ++k) {
            const int d = dq*16 + k;
            const float wv = Wk[(size_t)h*4096 + d*64 + i];
            qs += wv * bq[h*64 + d];
            wt[k] = f2bf(wv);
        }
#pragma unroll
        for (int kq = 0; kq < 4; ++kq) {
            bf16x4 o; o[0]=wt[kq*4]; o[1]=wt[kq*4+1]; o[2]=wt[kq*4+2]; o[3]=wt[kq*4+3];
            *(bf16x4*)(Wk_t + (size_t)h*4096 + i*64 + dq*16 + kq*4) = o;
        }
        red[t] = qs;
        __syncthreads();
        if (t < 64)
            qkb[h*64 + t] = (red[t] + red[t+64] + red[t+128] + red[t+192]) * 0.125f;
    }
}

// ---------------------------------------------------------------------------
// Kernel 1: fused query + qk (all-MFMA). (unchanged, passes)
// ---------------------------------------------------------------------------
__global__ __launch_bounds__(256) void queryqk_kernel(
        const short* __restrict__ Wq_bf, const short* __restrict__ tok_t,
        const short* __restrict__ Wk_t, const float* __restrict__ qkb,
        short* __restrict__ qk_bf) {
    __shared__ short q_ld[16 * 64];
    const int t = threadIdx.x, w = t >> 6, L = t & 63;
    const int lr = L & 15, hg = L >> 4;
    const int nh = blockIdx.x, n = nh >> 4, h = nh & 15;

    f32x4 acc = {0.f, 0.f, 0.f, 0.f};
    const short* aA = Wq_bf + (size_t)(h*64 + w*16 + lr) * 1024 + hg*8;
    const short* aB = tok_t + (size_t)n*16384 + (size_t)lr*1024 + hg*8;
#pragma unroll 4
    for (int ks = 0; ks < 32; ++ks) {
        const bf16x8 a = *(const bf16x8*)(aA + ks*32);
        const bf16x8 bb = *(const bf16x8*)(aB + ks*32);
        acc = MFMA16(a, bb, acc);
    }
    {
        bf16x4 qv; qv[0]=f2bf(acc[0]); qv[1]=f2bf(acc[1]); qv[2]=f2bf(acc[2]); qv[3]=f2bf(acc[3]);
        lds_st4(q_ld, (lr*128 + w*32 + hg*8) ^ SWZ(lr), qv);
    }
    __syncthreads();
    f32x4 a2 = {0.f, 0.f, 0.f, 0.f};
#pragma unroll
    for (int ks = 0; ks < 2; ++ks) {
        const bf16x8 a = *(const bf16x8*)(Wk_t + (size_t)h*4096 + (w*16 + lr)*64 + ks*32 + hg*8);
        const bf16x8 bb = lds_ld8(q_ld, (lr*128 + ks*64 + hg*16) ^ SWZ(lr));
        a2 = MFMA16(a, bb, a2);
    }
    const int i0 = w*16 + hg*4;
    bf16x4 qk4;
#pragma unroll
    for (int r = 0; r < 4; ++r)
        qk4[r] = f2bf(a2[r] * 0.125f + qkb[h*64 + i0 + r]);
    *(bf16x4*)(qk_bf + (size_t)nh*1024 + lr*64 + i0) = qk4;
}

// ---------------------------------------------------------------------------
// Kernel 2: WAVE-INDEPENDENT single-pass attention. Block per (n,h), 16 waves.
//   Wave w owns x-slab [w*64, w*64+64) end-to-end: it stages its own slab
//   (32-channel chunks) into its private 4 KB LDS region and MFMAs logits
//   from it — ZERO barriers until softmax. 16 desynced wave pipelines/CU
//   keep the memory pipe continuously fed (R7's lockstep got 53% util).
//   fc A-fragments re-read directly from global (L2/L3-hot; R5 showed the
//   re-read never reaches HBM) — f_ix LDS copy deleted. LDS 143 -> 76 KB.
//   Barriers: 5 total (softmax reduce x2, fc-dump, fcn, epilogue implicit).
// ---------------------------------------------------------------------------
__global__ __launch_bounds__(1024, 4) void attn_kernel(
        const float* __restrict__ feat, const short* __restrict__ qk_bf,
        const float* __restrict__ Wv, const float* __restrict__ bv,
        float* __restrict__ out0, float* __restrict__ out1) {
    __shared__ __align__(16) short f_lds[16 * 2048];  // 64 KB: 4 KB per wave
    __shared__ __align__(16) short wv_ld[64 * 64];    // 8 KB [d][i] bf16 swz
    __shared__ __align__(16) short fcn_ld[16 * 64];   // 2 KB [l][i] bf16 swz
    __shared__ float red_m[256], red_z[256];          // 2 KB

    const int t = threadIdx.x, w = t >> 6, L = t & 63;
    const int lr = L & 15, hg = L >> 4;
    const int nh = blockIdx.x, n = nh >> 4, h = nh & 15;
    const size_t fbase = (size_t)n*1048576 + (size_t)h*65536;
    char* region = (char*)f_lds + w*4096;   // this wave's private region

    const bf16x8 qb0 = *(const bf16x8*)(qk_bf + (size_t)nh*1024 + lr*64 + hg*8);
    const bf16x8 qb1 = *(const bf16x8*)(qk_bf + (size_t)nh*1024 + lr*64 + 32 + hg*8);

    const int xseg = (L & 15) * 4;          // x-local base for staging (this lane)
    const int ip   = (L >> 4) * 2;          // i-pair base within 8-row task
    const size_t xoff = (size_t)w*64 + xseg;

    f32x4 S[4];
#pragma unroll
    for (int tl = 0; tl < 4; ++tl) S[tl] = (f32x4){0.f, 0.f, 0.f, 0.f};

    // ============ logits: 2 chunks x {load 8KB -> copy -> LDS -> MFMA} ======
    // No __syncthreads anywhere here: region is wave-private, DS in-order.
#pragma unroll
    for (int c = 0; c < 2; ++c) {
        f32x4 v[8];
#pragma unroll
        for (int tk = 0; tk < 4; ++tk) {   // rows c*32 + tk*8 + ip, +1
            const size_t r0 = fbase + (size_t)(c*32 + tk*8 + ip)*1024 + xoff;
            v[2*tk]   = *(const f32x4*)(feat + r0);
            v[2*tk+1] = *(const f32x4*)(feat + r0 + 1024);
        }
#pragma unroll
        for (int tk = 0; tk < 4; ++tk) {   // fused out0 passthrough copy
            const size_t r0 = fbase + (size_t)(c*32 + tk*8 + ip)*1024 + xoff;
            *(f32x4*)(out0 + r0)        = v[2*tk];
            *(f32x4*)(out0 + r0 + 1024) = v[2*tk+1];
        }
#pragma unroll
        for (int tk = 0; tk < 4; ++tk) {   // region layout [x64][i32] bf16
            const int il = tk*8 + ip;      // i-local (pair il, il+1)
#pragma unroll
            for (int j = 0; j < 4; ++j) {
                const int x = xseg + j;
                bf16x2 pr; pr[0] = f2bf(v[2*tk][j]); pr[1] = f2bf(v[2*tk+1][j]);
                *(bf16x2*)(region + x*64 + ((il*2) ^ SW64(x))) = pr;
            }
        }
        const bf16x8 qb = c ? qb1 : qb0;
#pragma unroll
        for (int tl = 0; tl < 4; ++tl) {   // A-frag: row x, k = chunk's 32 i
            const int x = tl*16 + lr;
            const bf16x8 a = *(const bf16x8*)(region + x*64 + ((hg*16) ^ SW64(x)));
            S[tl] = MFMA16(a, qb, S[tl]);
        }
    }

    // ============ softmax over all 1024 x, per l = lr ============
    float m_l = -INFINITY;
#pragma unroll
    for (int tl = 0; tl < 4; ++tl)
#pragma unroll
        for (int r = 0; r < 4; ++r) m_l = fmaxf(m_l, S[tl][r]);
    m_l = fmaxf(m_l, __shfl_xor(m_l, 16));
    m_l = fmaxf(m_l, __shfl_xor(m_l, 32));
    if (L < 16) red_m[w*16 + L] = m_l;
    __syncthreads();
    float m_g = -INFINITY;
#pragma unroll
    for (int k = 0; k < 16; ++k) m_g = fmaxf(m_g, red_m[k*16 + lr]);
    float zl = 0.f;
#pragma unroll
    for (int tl = 0; tl < 4; ++tl)
#pragma unroll
        for (int r = 0; r < 4; ++r) {
            S[tl][r] = __expf(S[tl][r] - m_g);
            zl += S[tl][r];
        }
    // P -> own region as B-frag layout [l][x64] (first 2 KB; logits done)
#pragma unroll
    for (int tl = 0; tl < 4; ++tl) {
        bf16x4 pv; pv[0]=f2bf(S[tl][0]); pv[1]=f2bf(S[tl][1]); pv[2]=f2bf(S[tl][2]); pv[3]=f2bf(S[tl][3]);
        *(bf16x4*)(region + lr*128 + ((tl*32 + hg*8) ^ ((lr&7)<<4))) = pv;
    }
    zl += __shfl_xor(zl, 16);
    zl += __shfl_xor(zl, 32);
    if (L < 16) red_z[w*16 + L] = zl;
    {   // Wv -> LDS [d][i] bf16 (read in epilogue)
        const int d = t >> 4, i4 = (t & 15) * 4;
        const f32x4 wv4 = *(const f32x4*)(Wv + (size_t)h*4096 + d*64 + i4);
        bf16x4 wb; wb[0]=f2bf(wv4[0]); wb[1]=f2bf(wv4[1]); wb[2]=f2bf(wv4[2]); wb[3]=f2bf(wv4[3]);
        *(bf16x4*)((char*)wv_ld + d*128 + ((i4*2) ^ ((d&7)<<4))) = wb;
    }
    __syncthreads();
    float Zg = 0.f;
#pragma unroll
    for (int k = 0; k < 16; ++k) Zg += red_z[k*16 + lr];
    const float rz = 1.f / Zg;
    const bf16x8 pb0 = *(const bf16x8*)(region + lr*128 + ((     hg*16) ^ ((lr&7)<<4)));
    const bf16x8 pb1 = *(const bf16x8*)(region + lr*128 + ((64 + hg*16) ^ ((lr&7)<<4)));

    // ============ fc = f @ P ; A-frags straight from global (L2/L3-hot) ====
#pragma unroll
    for (int ct = 0; ct < 4; ++ct) {
        const size_t ro = fbase + (size_t)(ct*16 + lr)*1024 + w*64;
        const f32x4 g0 = *(const f32x4*)(feat + ro + hg*8);
        const f32x4 g1 = *(const f32x4*)(feat + ro + hg*8 + 4);
        const f32x4 g2 = *(const f32x4*)(feat + ro + 32 + hg*8);
        const f32x4 g3 = *(const f32x4*)(feat + ro + 32 + hg*8 + 4);
        bf16x8 A0, A1;
#pragma unroll
        for (int e = 0; e < 4; ++e) {
            A0[e] = f2bf(g0[e]); A0[4+e] = f2bf(g1[e]);
            A1[e] = f2bf(g2[e]); A1[4+e] = f2bf(g3[e]);
        }
        f32x4 acc = (f32x4){0.f, 0.f, 0.f, 0.f};
        acc = MFMA16(A0, pb0, acc);
        acc = MFMA16(A1, pb1, acc);
        *(f32x4*)(region + ct*1024 + L*16) = acc;   // dump partials (own region)
    }
    __syncthreads();

    // ============ reduce + normalize + epilogue (R7-verified mappings) =====
    if (w < 4) {   // wave w reduces i-tile w over 16 wave-partials
        f32x4 sum = (f32x4){0.f, 0.f, 0.f, 0.f};
#pragma unroll
        for (int wp = 0; wp < 16; ++wp)
            sum += *(const f32x4*)((const char*)f_lds + wp*4096 + w*1024 + L*16);
        bf16x4 fb;
#pragma unroll
        for (int r = 0; r < 4; ++r) fb[r] = f2bf(sum[r] * rz);
        *(bf16x4*)((char*)fcn_ld + lr*128 + ((w*32 + hg*8) ^ ((lr&7)<<4))) = fb;
    }
    __syncthreads();
    if (w < 4) {   // tok[d][l] = Wv @ fcn + bv; wave w owns d-tile w
        f32x4 acc = (f32x4){0.f, 0.f, 0.f, 0.f};
        const int d_m = w*16 + lr;
#pragma unroll
        for (int ks = 0; ks < 2; ++ks) {
            const bf16x8 a = lds_ld8(wv_ld, d_m*128 + ((ks*64 + hg*16) ^ ((d_m&7)<<4)));
            const bf16x8 b = lds_ld8(fcn_ld, lr*128 + ((ks*64 + hg*16) ^ ((lr&7)<<4)));
            acc = MFMA16(a, b, acc);
        }
#pragma unroll
        for (int r = 0; r < 4; ++r) {
            const int d = w*16 + hg*4 + r;
            out1[((size_t)n*1024 + h*64 + d)*16 + lr] = acc[r] + bv[h*64 + d];
        }
    }
}

// ---------------------------------------------------------------------------
extern "C" void kernel_launch(void* const* d_in, const int* in_sizes, int n_in,
                              void* d_out, int out_size, void* d_ws, size_t ws_size,
                              hipStream_t stream) {
    const float* feature = (const float*)d_in[0];
    const float* token   = (const float*)d_in[1];
    const float* Wq      = (const float*)d_in[2];
    const float* bq      = (const float*)d_in[3];
    const float* Wk      = (const float*)d_in[4];
    // d_in[5] = bk: provably unused (constant along softmax axis)
    const float* Wv      = (const float*)d_in[6];
    const float* bv      = (const float*)d_in[7];

    float* out0 = (float*)d_out;                      // feature passthrough
    float* out1 = out0 + (size_t)NB * 1024 * HW;      // tok [n][c][l]

    short* Wq_bf = (short*)d_ws;                               // 2 MB
    short* tok_t = Wq_bf + (size_t)1024 * 1024;                // 1 MB
    short* Wk_t  = tok_t + (size_t)NB * 16 * 1024;             // 128 KB
    short* qk_bf = Wk_t + (size_t)NHEAD * 64 * 64;             // 1 MB
    float* qkb   = (float*)(qk_bf + (size_t)NB * NHEAD * 1024);// 4 KB

    prep_kernel   <<<dim3(1072), 256, 0, stream>>>(Wq, token, Wk, bq, Wq_bf, tok_t, Wk_t, qkb);
    queryqk_kernel<<<dim3(NB * NHEAD), 256, 0, stream>>>(Wq_bf, tok_t, Wk_t, qkb, qk_bf);
    attn_kernel   <<<dim3(NB * NHEAD), 1024, 0, stream>>>(feature, qk_bf, Wv, bv, out0, out1);
}